// Round 1
// baseline (898.494 us; speedup 1.0000x reference)
//
#include <hip/hip_runtime.h>

#define B_TOT 1024
#define T_STEPS 24
#define F 64          // FILTERS
#define C2 128        // 2*FILTERS
#define FEAT 15
#define L_ENC 168
#define HID 128
#define K5 384        // N_DIL*FILTERS
#define R 4           // batch rows per block
#define BLK 512

__device__ __forceinline__ float sigmoidf_(float x) { return 1.0f / (1.0f + expf(-x)); }

__global__ __launch_bounds__(BLK) void decoder_v2_kernel(
    const float* __restrict__ dec_feat,   // (B,24,15)
    const float* __restrict__ dec_init,   // (B,1)
    const float* __restrict__ enc,        // (6,B,168,64)
    const float* __restrict__ gW1, const float* __restrict__ gb1,
    const float* __restrict__ gW2, const float* __restrict__ gb2,
    const float* __restrict__ gW3,
    const float* __restrict__ gW4, const float* __restrict__ gb4,
    const float* __restrict__ gW5, const float* __restrict__ gb5,
    const float* __restrict__ gW6, const float* __restrict__ gb6,
    float* __restrict__ out)              // (B,24)
{
  // ---- LDS ----
  __shared__ float sW1[16 * F];          //  4 KB
  __shared__ float sW23[F * C2 * 2];     // 64 KB, interleaved {W2[k][c], W3[k][c]}
  __shared__ float sW4[F * C2];          // 32 KB
  __shared__ float ring[7936];           // 31.75 KB: layers d=1,2,4,8,16 history
  __shared__ float stat[R][F];
  __shared__ float sInp[R][F];
  __shared__ float cur[R][16];
  __shared__ float dilbuf[R][C2];
  __shared__ float gated[R][F];
  __shared__ float skipbuf[R][K5];       // 6 KB
  __shared__ float sb1[F], sb2[C2], sb4[C2], sb5[HID], sW6c[HID];
  __shared__ float prevy[R];
  __shared__ float wsum[8];
  __shared__ float sb6;

  const int tid = threadIdx.x;
  const int b0 = blockIdx.x * R;
  const int r = tid >> 7;        // 0..3
  const int c = tid & 127;       // 0..127

  // ring base offsets (floats) for layers 0..4 (d = 1,2,4,8,16)
  const int ringBase0 = 0;       // 1  slot  * 256
  const int ringBase1 = 256;     // 2  slots
  const int ringBase2 = 768;     // 4  slots
  const int ringBase3 = 1792;    // 8  slots
  const int ringBase4 = 3840;    // 16 slots
  const int ringBases[5] = {ringBase0, ringBase1, ringBase2, ringBase3, ringBase4};

  // ---- preload weights into LDS ----
  for (int i = tid; i < 16 * F; i += BLK) sW1[i] = gW1[i];
  for (int i = tid; i < F * C2; i += BLK) { sW23[2*i] = gW2[i]; sW23[2*i+1] = gW3[i]; }
  for (int i = tid; i < F * C2; i += BLK) sW4[i] = gW4[i];
  if (tid < F) sb1[tid] = gb1[tid];
  if (tid < C2)            sb2[tid]        = gb2[tid];
  else if (tid < 2*C2)     sb4[tid - C2]   = gb4[tid - C2];
  else if (tid < 3*C2)     sb5[tid - 2*C2] = gb5[tid - 2*C2];
  else                     sW6c[tid - 3*C2] = gW6[tid - 3*C2];
  if (tid < R) prevy[tid] = dec_init[b0 + tid];
  if (tid == 0) sb6 = gb6[0];
  __syncthreads();

  for (int t = 0; t < T_STEPS; ++t) {
    // ---- phase 0: build cur; prefetch stat for dilation 0 (d=1) ----
    if (tid < R * 16) {
      int rr = tid >> 4, j = tid & 15;
      cur[rr][j] = (j == 0) ? prevy[rr]
                            : dec_feat[(b0 + rr) * (T_STEPS * FEAT) + t * FEAT + (j - 1)];
    } else if (tid >= 256) {
      int rr = (tid - 256) >> 6, cc = (tid - 256) & 63;
      float v;
      if (t >= 1) v = ring[ringBase0 + rr * F + cc];
      else        v = enc[((0 * B_TOT + (b0 + rr)) * L_ENC + (L_ENC + t - 1)) * F + cc];
      stat[rr][cc] = v;
    }
    __syncthreads();

    // ---- phase 1: inputs = tanh(cur @ W1 + b1)  (R x 64) ----
    if (tid < 256) {
      int rr = tid >> 6, cc = tid & 63;
      float acc = sb1[cc];
      #pragma unroll
      for (int k = 0; k < 16; ++k) acc += cur[rr][k] * sW1[k * F + cc];
      sInp[rr][cc] = tanhf(acc);
    }
    __syncthreads();

    // ---- dilation stack ----
    #pragma unroll
    for (int i = 0; i < 6; ++i) {
      const int d = 1 << i;
      // phase A: dilated[r][c] = b2[c] + sum_k stat[r][k]*W2[k][c] + inp[r][k]*W3[k][c]
      {
        float a0 = 0.f, a1 = 0.f, a2 = 0.f, a3 = 0.f;
        const float4* s4 = (const float4*)(&stat[r][0]);
        const float4* i4 = (const float4*)(&sInp[r][0]);
        #pragma unroll
        for (int k4 = 0; k4 < 16; ++k4) {
          float4 sv = s4[k4];
          float4 iv = i4[k4];
          const float2* w = (const float2*)(&sW23[(k4 * 4 * C2 + c) * 2]);
          float2 w0 = w[0 * C2];
          float2 w1 = w[1 * C2];
          float2 w2 = w[2 * C2];
          float2 w3 = w[3 * C2];
          a0 += sv.x * w0.x + iv.x * w0.y;
          a1 += sv.y * w1.x + iv.y * w1.y;
          a2 += sv.z * w2.x + iv.z * w2.y;
          a3 += sv.w * w3.x + iv.w * w3.y;
        }
        dilbuf[r][c] = ((a0 + a1) + (a2 + a3)) + sb2[c];
      }
      __syncthreads();

      // combine -> gated; idle half prefetches next dilation's state
      if (tid < 256) {
        int rr = tid >> 6, cc = tid & 63;
        float f = dilbuf[rr][cc], g = dilbuf[rr][cc + 64];
        gated[rr][cc] = tanhf(f) * sigmoidf_(g);
      } else if (i < 5) {
        int rr = (tid - 256) >> 6, cc = (tid - 256) & 63;
        const int dj = 2 << i;   // next dilation
        float v;
        if (t >= dj) {
          v = ring[ringBases[i + 1] + (t & (dj - 1)) * (R * F) + rr * F + cc];
        } else {
          v = enc[(((i + 1) * B_TOT + (b0 + rr)) * L_ENC + (L_ENC + t - dj)) * F + cc];
        }
        stat[rr][cc] = v;   // safe: phase A already consumed stat
      }
      __syncthreads();

      // phase B: out = gated @ W4 + b4 ; split skips / residuals
      {
        float a0 = 0.f, a1 = 0.f, a2 = 0.f, a3 = 0.f;
        const float4* g4 = (const float4*)(&gated[r][0]);
        #pragma unroll
        for (int k4 = 0; k4 < 16; ++k4) {
          float4 gv = g4[k4];
          const float* wp = &sW4[k4 * 4 * C2 + c];
          a0 += gv.x * wp[0 * C2];
          a1 += gv.y * wp[1 * C2];
          a2 += gv.z * wp[2 * C2];
          a3 += gv.w * wp[3 * C2];
        }
        float o = ((a0 + a1) + (a2 + a3)) + sb4[c];
        if (c < F) {
          skipbuf[r][i * F + c] = fmaxf(o, 0.0f);   // relu(skip)
        } else {
          float ni = sInp[r][c - F] + o;            // residual update
          sInp[r][c - F] = ni;
          if (i < 5) ring[ringBases[i] + (t & (d - 1)) * (R * F) + r * F + (c - F)] = ni;
        }
      }
      __syncthreads();
    }

    // ---- phase W5: h = relu(skip @ W5 + b5), W5 streamed from global (L1/L2-hot) ----
    float h;
    {
      float a0 = 0.f, a1 = 0.f, a2 = 0.f, a3 = 0.f;
      const float4* sk4 = (const float4*)(&skipbuf[r][0]);
      #pragma unroll 8
      for (int k4 = 0; k4 < K5 / 4; ++k4) {
        float4 sv = sk4[k4];
        const float* wp = &gW5[(k4 * 4) * HID + c];
        a0 += sv.x * wp[0 * HID];
        a1 += sv.y * wp[1 * HID];
        a2 += sv.z * wp[2 * HID];
        a3 += sv.w * wp[3 * HID];
      }
      h = fmaxf(((a0 + a1) + (a2 + a3)) + sb5[c], 0.0f);
    }

    // ---- phase W6: y = h @ W6 + b6 (wave reduce over 128 cols = 2 waves/row) ----
    float v = h * sW6c[c];
    #pragma unroll
    for (int off = 32; off >= 1; off >>= 1) v += __shfl_xor(v, off);
    if ((tid & 63) == 0) wsum[tid >> 6] = v;
    __syncthreads();
    if (tid < R) {
      float y = wsum[2 * tid] + wsum[2 * tid + 1] + sb6;
      prevy[tid] = y;
      out[(b0 + tid) * T_STEPS + t] = y;
    }
    __syncthreads();
  }
}

extern "C" void kernel_launch(void* const* d_in, const int* in_sizes, int n_in,
                              void* d_out, int out_size, void* d_ws, size_t ws_size,
                              hipStream_t stream) {
  const float* dec_feat = (const float*)d_in[0];
  const float* dec_init = (const float*)d_in[1];
  const float* enc      = (const float*)d_in[2];
  const float* W1 = (const float*)d_in[3];
  const float* b1 = (const float*)d_in[4];
  const float* W2 = (const float*)d_in[5];
  const float* b2 = (const float*)d_in[6];
  const float* W3 = (const float*)d_in[7];
  const float* W4 = (const float*)d_in[8];
  const float* b4 = (const float*)d_in[9];
  const float* W5 = (const float*)d_in[10];
  const float* b5 = (const float*)d_in[11];
  const float* W6 = (const float*)d_in[12];
  const float* b6 = (const float*)d_in[13];
  float* out = (float*)d_out;

  dim3 grid(B_TOT / R);
  dim3 block(BLK);
  decoder_v2_kernel<<<grid, block, 0, stream>>>(
      dec_feat, dec_init, enc, W1, b1, W2, b2, W3, W4, b4, W5, b5, W6, b6, out);
}

// Round 2
// 740.413 us; speedup vs baseline: 1.2135x; 1.2135x over previous
//
#include <hip/hip_runtime.h>

#define B_TOT 1024
#define T_STEPS 24
#define F 64          // FILTERS
#define C2 128        // 2*FILTERS
#define FEAT 15
#define L_ENC 168
#define HID 128
#define K5 384        // N_DIL*FILTERS
#define R 4           // batch rows per block
#define BLK 512

__device__ __forceinline__ float rl(float v, int l) {
  return __uint_as_float(__builtin_amdgcn_readlane(__float_as_uint(v), (unsigned)l));
}
__device__ __forceinline__ float sigmoidf_(float x) { return 1.0f / (1.0f + expf(-x)); }

// Wave layout: 8 waves/block. wave w = (r = w>>1, h = w&1).
// Lane c' of wave (r,h) owns output column cg = h*64 + c' of the 128-wide matmuls,
// and holds activation channel c' of row r in a register (broadcast via v_readlane).
// Weights live in VGPRs (per-lane column slices) -> zero LDS in the FMA loops.
__global__ __launch_bounds__(BLK, 2) void decoder_v3_kernel(
    const float* __restrict__ dec_feat,   // (B,24,15)
    const float* __restrict__ dec_init,   // (B,1)
    const float* __restrict__ enc,        // (6,B,168,64)
    const float* __restrict__ gW1, const float* __restrict__ gb1,
    const float* __restrict__ gW2, const float* __restrict__ gb2,
    const float* __restrict__ gW3,
    const float* __restrict__ gW4, const float* __restrict__ gb4,
    const float* __restrict__ gW5, const float* __restrict__ gb5,
    const float* __restrict__ gW6, const float* __restrict__ gb6,
    float* __restrict__ out)              // (B,24)
{
  __shared__ float ring[7936];            // layers d=1,2,4,8,16; base = 256*(d-1), slot stride 256
  __shared__ float skipbuf[R][K5];        // 6 KB
  __shared__ float fbuf[R][F], gbuf[R][F];
  __shared__ float xbuf[R][F];
  __shared__ float2 P2[8][R][F];          // W5 partials: [wave][row][lane] -> (col lane, col lane+64)
  __shared__ float sb5[HID], sW6[HID];
  __shared__ float prevy[R];
  __shared__ float wsum[8];
  __shared__ float sb6v;

  const int tid  = threadIdx.x;
  const int wv   = tid >> 6;       // 0..7
  const int lane = tid & 63;
  const int r    = wv >> 1;        // row 0..3
  const int h    = wv & 1;         // column half
  const int cg   = h * F + lane;   // output column 0..127
  const int b0   = blockIdx.x * R;

  // ---- persistent per-lane weight columns (VGPRs) ----
  float w1c[16], w2c[F], w3c[F], w4c[F];
  #pragma unroll
  for (int k = 0; k < 16; ++k) w1c[k] = gW1[k * F + lane];
  #pragma unroll
  for (int k = 0; k < F; ++k)  w2c[k] = gW2[k * C2 + cg];
  #pragma unroll
  for (int k = 0; k < F; ++k)  w3c[k] = gW3[k * C2 + cg];
  #pragma unroll
  for (int k = 0; k < F; ++k)  w4c[k] = gW4[k * C2 + cg];
  const float b1c = gb1[lane];
  const float b2c = gb2[cg];
  const float b4c = gb4[cg];

  if (tid < R) prevy[tid] = dec_init[b0 + tid];
  if (tid < HID) sb5[tid] = gb5[tid];
  else if (tid < 2 * HID) sW6[tid - HID] = gW6[tid - HID];
  if (tid == 0) sb6v = gb6[0];
  __syncthreads();

  for (int t = 0; t < T_STEPS; ++t) {
    // ---- cur + W1: x[r][lane] = tanh(sum_k cur[k]*W1[k][lane] + b1) (both waves redundantly) ----
    float curv = 0.0f;
    if (lane == 0) curv = prevy[r];
    else if (lane < 16) curv = dec_feat[(b0 + r) * (T_STEPS * FEAT) + t * FEAT + (lane - 1)];
    float acc1 = b1c;
    #pragma unroll
    for (int k = 0; k < 16; ++k) acc1 = fmaf(rl(curv, k), w1c[k], acc1);
    float x = tanhf(acc1);

    // stat for dilation 0 (d=1)
    float stat;
    if (t >= 1) stat = ring[r * F + lane];  // base 0, slot 0
    else        stat = enc[((size_t)(b0 + r) * L_ENC + (L_ENC + t - 1)) * F + lane];

    // ---- dilation stack ----
    for (int i = 0; i < 6; ++i) {
      const int d = 1 << i;
      // phase A: dilated[r][cg] = b2 + stat@W2 + x@W3   (pure VALU)
      float accS = b2c, accI = 0.0f;
      #pragma unroll
      for (int k = 0; k < F; ++k) {
        accS = fmaf(rl(stat, k), w2c[k], accS);
        accI = fmaf(rl(x, k),    w3c[k], accI);
      }
      const float dil = accS + accI;
      if (h == 0) fbuf[r][lane] = dil;
      else        gbuf[r][lane] = dil;

      // prefetch next dilation's state while the bounce settles
      float stat_n = 0.0f;
      if (i < 5) {
        const int d2 = d << 1;
        if (t >= d2)
          stat_n = ring[256 * (d2 - 1) + (t & (d2 - 1)) * (R * F) + r * F + lane];
        else
          stat_n = enc[((size_t)((i + 1) * B_TOT + b0 + r) * L_ENC + (L_ENC + t - d2)) * F + lane];
      }
      __syncthreads();

      const float fv = (h == 0) ? dil : fbuf[r][lane];
      const float gv = (h == 0) ? gbuf[r][lane] : dil;
      const float gated = tanhf(fv) * sigmoidf_(gv);

      // phase B: out[r][cg] = gated @ W4 + b4   (pure VALU)
      float accB = b4c;
      #pragma unroll
      for (int k = 0; k < F; ++k) accB = fmaf(rl(gated, k), w4c[k], accB);

      if (h == 0) {
        skipbuf[r][i * F + lane] = fmaxf(accB, 0.0f);   // skip (cols 0..63)
      } else {
        x += accB;                                      // residual (cols 64..127)
        xbuf[r][lane] = x;
        if (i < 5) ring[256 * (d - 1) + (t & (d - 1)) * (R * F) + r * F + lane] = x;
      }
      __syncthreads();
      if (h == 0) x = xbuf[r][lane];
      stat = stat_n;
    }

    // ---- W5: h = relu(skip @ W5 + b5); k-split mod-8 across waves (W5 read once/CU) ----
    float vsk0, vsk1, vsk2, vsk3;
    {
      int kk = wv + 8 * lane;            // lane l holds skip[.][wv+8l] (l<48 valid)
      int kkc = kk < K5 ? kk : 0;
      vsk0 = skipbuf[0][kkc]; vsk1 = skipbuf[1][kkc];
      vsk2 = skipbuf[2][kkc]; vsk3 = skipbuf[3][kkc];
    }
    float a00 = 0, a01 = 0, a10 = 0, a11 = 0, a20 = 0, a21 = 0, a30 = 0, a31 = 0;
    const float* w5p = gW5 + (size_t)wv * HID + lane;
    #pragma unroll 4
    for (int j = 0; j < 48; ++j) {
      const float wa = w5p[0];
      const float wb = w5p[64];
      const float s0 = rl(vsk0, j), s1 = rl(vsk1, j), s2 = rl(vsk2, j), s3 = rl(vsk3, j);
      a00 = fmaf(s0, wa, a00); a01 = fmaf(s0, wb, a01);
      a10 = fmaf(s1, wa, a10); a11 = fmaf(s1, wb, a11);
      a20 = fmaf(s2, wa, a20); a21 = fmaf(s2, wb, a21);
      a30 = fmaf(s3, wa, a30); a31 = fmaf(s3, wb, a31);
      w5p += 8 * HID;
    }
    P2[wv][0][lane] = make_float2(a00, a01);
    P2[wv][1][lane] = make_float2(a10, a11);
    P2[wv][2][lane] = make_float2(a20, a21);
    P2[wv][3][lane] = make_float2(a30, a31);
    __syncthreads();

    // ---- finalize h, then y = h @ W6 + b6 ----
    {
      const int rr = tid >> 7;          // 0..3
      const int cc = tid & 127;         // wave-uniform half: cc>>6 constant per wave
      const int ll = cc & 63;
      float s = sb5[cc];
      if ((cc >> 6) == 0) {
        #pragma unroll
        for (int w8 = 0; w8 < 8; ++w8) s += P2[w8][rr][ll].x;
      } else {
        #pragma unroll
        for (int w8 = 0; w8 < 8; ++w8) s += P2[w8][rr][ll].y;
      }
      const float hv = fmaxf(s, 0.0f);
      float v = hv * sW6[cc];
      #pragma unroll
      for (int off = 32; off >= 1; off >>= 1) v += __shfl_xor(v, off);
      if ((tid & 63) == 0) wsum[tid >> 6] = v;
    }
    __syncthreads();
    if (tid < R) {
      const float y = wsum[2 * tid] + wsum[2 * tid + 1] + sb6v;
      prevy[tid] = y;
      out[(b0 + tid) * T_STEPS + t] = y;
    }
    __syncthreads();
  }
}

extern "C" void kernel_launch(void* const* d_in, const int* in_sizes, int n_in,
                              void* d_out, int out_size, void* d_ws, size_t ws_size,
                              hipStream_t stream) {
  const float* dec_feat = (const float*)d_in[0];
  const float* dec_init = (const float*)d_in[1];
  const float* enc      = (const float*)d_in[2];
  const float* W1 = (const float*)d_in[3];
  const float* b1 = (const float*)d_in[4];
  const float* W2 = (const float*)d_in[5];
  const float* b2 = (const float*)d_in[6];
  const float* W3 = (const float*)d_in[7];
  const float* W4 = (const float*)d_in[8];
  const float* b4 = (const float*)d_in[9];
  const float* W5 = (const float*)d_in[10];
  const float* b5 = (const float*)d_in[11];
  const float* W6 = (const float*)d_in[12];
  const float* b6 = (const float*)d_in[13];
  float* out = (float*)d_out;

  dim3 grid(B_TOT / R);
  dim3 block(BLK);
  decoder_v3_kernel<<<grid, block, 0, stream>>>(
      dec_feat, dec_init, enc, W1, b1, W2, b2, W3, W4, b4, W5, b5, W6, b6, out);
}